// Round 8
// baseline (47.302 us; speedup 1.0000x reference)
//
#include <hip/hip_runtime.h>
#include <hip/hip_bf16.h>

#define T_TOKENS 2048
#define DIM 256
#define NLEV 8

using bf16x8 = __attribute__((ext_vector_type(8))) short;
using f32x4  = __attribute__((ext_vector_type(4))) float;

__device__ __forceinline__ unsigned short f2bf(float f) {
    union { float f; unsigned u; } v; v.f = f;
    unsigned r = v.u + 0x7FFFu + ((v.u >> 16) & 1u);   // RNE
    return (unsigned short)(r >> 16);
}

// ---------------- Kernel 1: routing (exact fp32) ----------------
__global__ __launch_bounds__(256) void route_kernel(
    const float* __restrict__ x, const float* __restrict__ w1s,
    const float* __restrict__ b1s,
    float* __restrict__ pw,   // [T][8]
    int*   __restrict__ pc)   // [T] pathcode in [256,511]
{
    int wave = threadIdx.x >> 6;
    int lane = threadIdx.x & 63;
    int t = blockIdx.x * 4 + wave;    // grid = 512 -> t < 2048

    const float4 xv = *reinterpret_cast<const float4*>(x + (size_t)t * DIM + lane * 4);
    int p = 1;
    float keep = 0.0f;
    #pragma unroll
    for (int lvl = 0; lvl < NLEV; ++lvl) {
        int node = p - 1;
        const float4 wv = *reinterpret_cast<const float4*>(w1s + (size_t)node * DIM + lane * 4);
        float s = xv.x * wv.x + xv.y * wv.y + xv.z * wv.z + xv.w * wv.w;
        #pragma unroll
        for (int off = 32; off; off >>= 1) s += __shfl_xor(s, off);
        float score = s + b1s[node];
        float a = fabsf(score);
        float g = a * 0.5f * (1.0f + erff(a * 0.70710678118654752f));  // exact GELU
        if (lane == lvl) keep = g;
        int choice = (score > 0.0f) ? 1 : 0;   // sign(0)->choice 0 matches ref
        p = 2 * p + choice;
    }
    if (lane < NLEV) pw[(size_t)t * NLEV + lane] = keep;
    if (lane == 0) pc[t] = p;
}

// ---------------- Kernel 2: counting sort + unit enumeration (1 block) ----------------
__global__ __launch_bounds__(256) void sort_kernel(
    const int* __restrict__ pc,
    int* __restrict__ order, unsigned* __restrict__ units, int* __restrict__ ucount)
{
    __shared__ int hist[256];
    __shared__ int offs[256];
    __shared__ int cums[257];
    __shared__ int wpart[4];
    int tid = threadIdx.x;
    hist[tid] = 0;
    __syncthreads();

    int myPc[8];
    #pragma unroll
    for (int i = 0; i < 8; ++i) {
        int t = tid * 8 + i;
        myPc[i] = pc[t];
        atomicAdd(&hist[myPc[i] - 256], 1);
    }
    __syncthreads();

    if (tid < 64) {
        int lane = tid;
        int v0 = hist[lane * 4 + 0], v1 = hist[lane * 4 + 1];
        int v2 = hist[lane * 4 + 2], v3 = hist[lane * 4 + 3];
        int sum = v0 + v1 + v2 + v3;
        int scan = sum;
        #pragma unroll
        for (int off = 1; off < 64; off <<= 1) {
            int n = __shfl_up(scan, off);
            if (lane >= off) scan += n;
        }
        int excl = scan - sum;
        offs[lane * 4 + 0] = excl;
        offs[lane * 4 + 1] = excl + v0;
        offs[lane * 4 + 2] = excl + v0 + v1;
        offs[lane * 4 + 3] = excl + v0 + v1 + v2;
    }
    __syncthreads();

    cums[tid] = offs[tid];
    if (tid == 0) cums[256] = T_TOKENS;
    __syncthreads();

    #pragma unroll
    for (int i = 0; i < 8; ++i) {
        int t = tid * 8 + i;
        int bin = myPc[i] - 256;
        int pos = atomicAdd(&offs[bin], 1);
        order[pos] = t;
    }

    int nch = 0, s = 0, e = 0, l = 0;
    if (tid < 255) {
        int q = tid + 1;
        l = 31 - __clz(q);
        int shift = 8 - l;
        int lo = (q << shift) - 256;
        int hi = ((q + 1) << shift) - 256;
        s = cums[lo];
        e = cums[hi];
        nch = (e - s + 63) >> 6;
    }
    int lane = tid & 63, w = tid >> 6;
    int scan = nch;
    #pragma unroll
    for (int off = 1; off < 64; off <<= 1) {
        int n = __shfl_up(scan, off);
        if (lane >= off) scan += n;
    }
    if (lane == 63) wpart[w] = scan;
    __syncthreads();
    int pre = 0;
    for (int k = 0; k < w; ++k) pre += wpart[k];
    int base = pre + scan - nch;
    for (int j = 0; j < nch; ++j) {
        int st = s + j * 64;
        int c = e - st; if (c > 64) c = 64;
        units[base + j] = (unsigned)tid | ((unsigned)l << 8) |
                          ((unsigned)st << 11) | ((unsigned)c << 22);
    }
    if (tid == 255) *ucount = pre + scan;
}

// ---------------- Kernel 3: per-unit col-split GEMM, 4-deep B prefetch ----------------
// Block = (unit, col-half). 4 waves; wave wv covers cols ch*128 + wv*32 .. +31.
// A: 64x256 bf16 (32 KiB, swizzled). B: 32k x 128c bf16 panels, dbuf (2 x 8 KiB).
// B global loads staged 4 panels deep in registers (La0..La3) so each panel's
// vmcnt wait covers loads issued 3 iterations earlier -> continuous load stream.
__global__ __launch_bounds__(256, 3) void out_kernel(
    const float* __restrict__ x, const float* __restrict__ w2s,
    const float* __restrict__ b2s, const float* __restrict__ pw,
    const int* __restrict__ order, const unsigned* __restrict__ units,
    const int* __restrict__ ucount, float* __restrict__ lvlbuf)
{
    __shared__ unsigned short As[16384];     // granule(row,gk) = row*32 + (gk ^ (row&7))
    __shared__ unsigned short Bs[2][4096];   // granule g = kgrp*128+col; sidx = g ^ ((g>>3)&7)

    int u = blockIdx.x >> 1;
    int ch = blockIdx.x & 1;
    if (u >= *ucount) return;
    unsigned d = units[u];
    int node  = (int)(d & 255u);
    int lvl   = (int)((d >> 8) & 7u);
    int start = (int)((d >> 11) & 2047u);
    int cnt   = (int)((d >> 22) & 127u);

    int tid = threadIdx.x;
    int wv = tid >> 6, lane = tid & 63;
    int l15 = lane & 15, kg = lane >> 4;

    const float* w2n = w2s + ((size_t)node << 16) + ch * 128;

    float2 La0[8], La1[8], La2[8], La3[8];
    auto loadB = [&](int p, float2 (&La)[8]) {
        const float* bp = w2n + (size_t)(p * 32 + wv * 8) * DIM + lane * 2;
        #pragma unroll
        for (int j = 0; j < 8; ++j)
            La[j] = *reinterpret_cast<const float2*>(bp + (size_t)j * DIM);
    };
    auto writeB = [&](unsigned short* bs, const float2 (&La)[8]) {
        bf16x8 v0, v1;
        #pragma unroll
        for (int j = 0; j < 8; ++j) {
            v0[j] = (short)f2bf(La[j].x);
            v1[j] = (short)f2bf(La[j].y);
        }
        int g0 = wv * 128 + lane * 2;
        int g1 = g0 + 1;
        *reinterpret_cast<bf16x8*>(&bs[(g0 ^ ((g0 >> 3) & 7)) * 8]) = v0;
        *reinterpret_cast<bf16x8*>(&bs[(g1 ^ ((g1 >> 3) & 7)) * 8]) = v1;
    };

    loadB(0, La0);
    loadB(1, La1);
    loadB(2, La2);
    loadB(3, La3);

    // stage A: thread -> (row = tid>>2, seg = tid&3 covering k 64*seg..+63)
    {
        int r = tid >> 2, seg = tid & 3;
        if (r < cnt) {
            int t = order[start + r];
            const float* xp = x + (size_t)t * DIM + seg * 64;
            #pragma unroll
            for (int g = 0; g < 8; ++g) {
                float4 a0 = *reinterpret_cast<const float4*>(xp + g * 8);
                float4 a1 = *reinterpret_cast<const float4*>(xp + g * 8 + 4);
                bf16x8 v;
                v[0] = (short)f2bf(a0.x); v[1] = (short)f2bf(a0.y);
                v[2] = (short)f2bf(a0.z); v[3] = (short)f2bf(a0.w);
                v[4] = (short)f2bf(a1.x); v[5] = (short)f2bf(a1.y);
                v[6] = (short)f2bf(a1.z); v[7] = (short)f2bf(a1.w);
                int gk = seg * 8 + g;
                int gg = r * 32 + (gk ^ (r & 7));
                *reinterpret_cast<bf16x8*>(&As[gg * 8]) = v;
            }
        }
    }
    writeB(Bs[0], La0);
    __syncthreads();

    f32x4 acc[4][2];
    #pragma unroll
    for (int m = 0; m < 4; ++m)
        #pragma unroll
        for (int nb = 0; nb < 2; ++nb) acc[m][nb] = (f32x4){0.f, 0.f, 0.f, 0.f};

    #pragma unroll
    for (int p = 0; p < 8; ++p) {
        // issue loads for panel p+4 into the slot just consumed by writeB(p) last iter
        if (p + 4 < 8) {
            if ((p & 3) == 0)      loadB(p + 4, La0);
            else if ((p & 3) == 1) loadB(p + 4, La1);
            else if ((p & 3) == 2) loadB(p + 4, La2);
            else                   loadB(p + 4, La3);
        }
        unsigned short* bs = Bs[p & 1];
        bf16x8 a[4], b[2];
        #pragma unroll
        for (int nb = 0; nb < 2; ++nb) {
            int g = kg * 128 + wv * 32 + nb * 16 + l15;
            b[nb] = *reinterpret_cast<bf16x8*>(&bs[(g ^ ((g >> 3) & 7)) * 8]);
        }
        #pragma unroll
        for (int m = 0; m < 4; ++m) if (m * 16 < cnt) {
            int row = m * 16 + l15;
            int g = row * 32 + ((p * 4 + kg) ^ (row & 7));
            a[m] = *reinterpret_cast<bf16x8*>(&As[g * 8]);
        }
        #pragma unroll
        for (int m = 0; m < 4; ++m) if (m * 16 < cnt)
            #pragma unroll
            for (int nb = 0; nb < 2; ++nb)
                acc[m][nb] = __builtin_amdgcn_mfma_f32_16x16x32_bf16(a[m], b[nb], acc[m][nb], 0, 0, 0);
        if (p < 7) {
            int q = (p + 1) & 3;   // unroll-literal
            if (q == 0)      writeB(Bs[(p + 1) & 1], La0);
            else if (q == 1) writeB(Bs[(p + 1) & 1], La1);
            else if (q == 2) writeB(Bs[(p + 1) & 1], La2);
            else             writeB(Bs[(p + 1) & 1], La3);
        }
        __syncthreads();
    }

    // epilogue: lvlbuf[lvl][tok][col] = pw[tok][lvl] * (acc + bias)  (plain store)
    float bias[2];
    #pragma unroll
    for (int nb = 0; nb < 2; ++nb)
        bias[nb] = b2s[((size_t)node << 8) + ch * 128 + wv * 32 + nb * 16 + l15];

    float* dst = lvlbuf + ((size_t)lvl << 19);   // 2048*256 = 1<<19 per level

    #pragma unroll
    for (int m = 0; m < 4; ++m) if (m * 16 < cnt) {
        #pragma unroll
        for (int j = 0; j < 4; ++j) {
            int r = m * 16 + kg * 4 + j;
            if (r < cnt) {
                int t = order[start + r];
                float w = pw[(size_t)t * NLEV + lvl];
                #pragma unroll
                for (int nb = 0; nb < 2; ++nb) {
                    float val = w * (acc[m][nb][j] + bias[nb]);
                    dst[(size_t)t * DIM + ch * 128 + wv * 32 + nb * 16 + l15] = val;
                }
            }
        }
    }
}

// ---------------- Kernel 4: reduce 8 level-buffers -> out ----------------
__global__ __launch_bounds__(256) void reduce_kernel(
    const float* __restrict__ lvlbuf, float* __restrict__ out)
{
    int idx = blockIdx.x * 256 + threadIdx.x;          // float4 index, < 131072
    const float4* lb = reinterpret_cast<const float4*>(lvlbuf);
    float4 s = lb[idx];
    #pragma unroll
    for (int l = 1; l < NLEV; ++l) {
        float4 v = lb[(size_t)l * 131072 + idx];
        s.x += v.x; s.y += v.y; s.z += v.z; s.w += v.w;
    }
    reinterpret_cast<float4*>(out)[idx] = s;
}

extern "C" void kernel_launch(void* const* d_in, const int* in_sizes, int n_in,
                              void* d_out, int out_size, void* d_ws, size_t ws_size,
                              hipStream_t stream) {
    const float* x   = (const float*)d_in[0];
    const float* w1s = (const float*)d_in[1];
    const float* b1s = (const float*)d_in[2];
    const float* w2s = (const float*)d_in[3];
    const float* b2s = (const float*)d_in[4];
    float* out = (float*)d_out;

    float* pw       = (float*)d_ws;                    // 2048*8 f32   (64 KB)
    int* pc         = (int*)(pw + T_TOKENS * NLEV);    // 2048
    int* order      = pc + T_TOKENS;                   // 2048
    unsigned* units = (unsigned*)(order + T_TOKENS);   // 512
    int* ucount     = (int*)(units + 512);             // 1
    float* lvlbuf   = (float*)((char*)d_ws + (1 << 20));  // 8 * 2048 * 256 f32 = 16 MB

    route_kernel<<<T_TOKENS / 4, 256, 0, stream>>>(x, w1s, b1s, pw, pc);
    sort_kernel<<<1, 256, 0, stream>>>(pc, order, units, ucount);
    out_kernel<<<1024, 256, 0, stream>>>(x, w2s, b2s, pw, order, units, ucount, lvlbuf);
    reduce_kernel<<<512, 256, 0, stream>>>(lvlbuf, out);
}

// Round 9
// 45.039 us; speedup vs baseline: 1.0503x; 1.0503x over previous
//
#include <hip/hip_runtime.h>
#include <hip/hip_bf16.h>

#define T_TOKENS 2048
#define DIM 256
#define NLEV 8

using bf16x8 = __attribute__((ext_vector_type(8))) short;
using f32x4  = __attribute__((ext_vector_type(4))) float;

__device__ __forceinline__ unsigned short f2bf(float f) {
    union { float f; unsigned u; } v; v.f = f;
    unsigned r = v.u + 0x7FFFu + ((v.u >> 16) & 1u);   // RNE
    return (unsigned short)(r >> 16);
}

// ---------------- Kernel 1: routing (exact fp32) ----------------
__global__ __launch_bounds__(256) void route_kernel(
    const float* __restrict__ x, const float* __restrict__ w1s,
    const float* __restrict__ b1s,
    float* __restrict__ pw,   // [T][8]
    int*   __restrict__ pc)   // [T] pathcode in [256,511]
{
    int wave = threadIdx.x >> 6;
    int lane = threadIdx.x & 63;
    int t = blockIdx.x * 4 + wave;    // grid = 512 -> t < 2048

    const float4 xv = *reinterpret_cast<const float4*>(x + (size_t)t * DIM + lane * 4);
    int p = 1;
    float keep = 0.0f;
    #pragma unroll
    for (int lvl = 0; lvl < NLEV; ++lvl) {
        int node = p - 1;
        const float4 wv = *reinterpret_cast<const float4*>(w1s + (size_t)node * DIM + lane * 4);
        float s = xv.x * wv.x + xv.y * wv.y + xv.z * wv.z + xv.w * wv.w;
        #pragma unroll
        for (int off = 32; off; off >>= 1) s += __shfl_xor(s, off);
        float score = s + b1s[node];
        float a = fabsf(score);
        float g = a * 0.5f * (1.0f + erff(a * 0.70710678118654752f));  // exact GELU
        if (lane == lvl) keep = g;
        int choice = (score > 0.0f) ? 1 : 0;   // sign(0)->choice 0 matches ref
        p = 2 * p + choice;
    }
    if (lane < NLEV) pw[(size_t)t * NLEV + lane] = keep;
    if (lane == 0) pc[t] = p;
}

// ---------------- Kernel 2: counting sort + unit enumeration (1 block) ----------------
__global__ __launch_bounds__(256) void sort_kernel(
    const int* __restrict__ pc,
    int* __restrict__ order, unsigned* __restrict__ units, int* __restrict__ ucount)
{
    __shared__ int hist[256];
    __shared__ int offs[256];
    __shared__ int cums[257];
    __shared__ int wpart[4];
    int tid = threadIdx.x;
    hist[tid] = 0;
    __syncthreads();

    int myPc[8];
    #pragma unroll
    for (int i = 0; i < 8; ++i) {
        int t = tid * 8 + i;
        myPc[i] = pc[t];
        atomicAdd(&hist[myPc[i] - 256], 1);
    }
    __syncthreads();

    if (tid < 64) {
        int lane = tid;
        int v0 = hist[lane * 4 + 0], v1 = hist[lane * 4 + 1];
        int v2 = hist[lane * 4 + 2], v3 = hist[lane * 4 + 3];
        int sum = v0 + v1 + v2 + v3;
        int scan = sum;
        #pragma unroll
        for (int off = 1; off < 64; off <<= 1) {
            int n = __shfl_up(scan, off);
            if (lane >= off) scan += n;
        }
        int excl = scan - sum;
        offs[lane * 4 + 0] = excl;
        offs[lane * 4 + 1] = excl + v0;
        offs[lane * 4 + 2] = excl + v0 + v1;
        offs[lane * 4 + 3] = excl + v0 + v1 + v2;
    }
    __syncthreads();

    cums[tid] = offs[tid];
    if (tid == 0) cums[256] = T_TOKENS;
    __syncthreads();

    #pragma unroll
    for (int i = 0; i < 8; ++i) {
        int t = tid * 8 + i;
        int bin = myPc[i] - 256;
        int pos = atomicAdd(&offs[bin], 1);
        order[pos] = t;
    }

    int nch = 0, s = 0, e = 0, l = 0;
    if (tid < 255) {
        int q = tid + 1;
        l = 31 - __clz(q);
        int shift = 8 - l;
        int lo = (q << shift) - 256;
        int hi = ((q + 1) << shift) - 256;
        s = cums[lo];
        e = cums[hi];
        nch = (e - s + 63) >> 6;
    }
    int lane = tid & 63, w = tid >> 6;
    int scan = nch;
    #pragma unroll
    for (int off = 1; off < 64; off <<= 1) {
        int n = __shfl_up(scan, off);
        if (lane >= off) scan += n;
    }
    if (lane == 63) wpart[w] = scan;
    __syncthreads();
    int pre = 0;
    for (int k = 0; k < w; ++k) pre += wpart[k];
    int base = pre + scan - nch;
    for (int j = 0; j < nch; ++j) {
        int st = s + j * 64;
        int c = e - st; if (c > 64) c = 64;
        units[base + j] = (unsigned)tid | ((unsigned)l << 8) |
                          ((unsigned)st << 11) | ((unsigned)c << 22);
    }
    if (tid == 255) *ucount = pre + scan;
}

// ---------------- Kernel 3: per-unit col-split GEMM, wave-private B, NO barriers in K-loop ----------------
// Block = (unit, col-half). 4 waves; wave wv owns cols ch*128 + wv*32 .. +31.
// A: 64x256 bf16 shared LDS (32 KiB, swizzled), read-only after one barrier.
// B: per-wave private 2 KiB x 2 dbuf transpose buffers -> no __syncthreads in
// the panel loop -> no vmcnt(0) barrier drain -> loads stay in flight.
__global__ __launch_bounds__(256, 3) void out_kernel(
    const float* __restrict__ x, const float* __restrict__ w2s,
    const float* __restrict__ b2s, const float* __restrict__ pw,
    const int* __restrict__ order, const unsigned* __restrict__ units,
    const int* __restrict__ ucount, float* __restrict__ lvlbuf)
{
    __shared__ unsigned short As[16384];          // granule(row,gk) = row*32 + (gk ^ (row&7))
    __shared__ unsigned short BsW[4][2][1024];    // per-wave: granule gi = kgq*32+col; sidx = gi ^ ((gi>>3)&7)

    int u = blockIdx.x >> 1;
    int ch = blockIdx.x & 1;
    if (u >= *ucount) return;
    unsigned d = units[u];
    int node  = (int)(d & 255u);
    int lvl   = (int)((d >> 8) & 7u);
    int start = (int)((d >> 11) & 2047u);
    int cnt   = (int)((d >> 22) & 127u);

    int tid = threadIdx.x;
    int wv = tid >> 6, lane = tid & 63;
    int l15 = lane & 15, kg = lane >> 4;

    // this lane's fixed global column for B loads
    const float* w2c = w2s + ((size_t)node << 16) + ch * 128 + wv * 32 + (lane & 31);
    int rg = (lane >> 5) * 8;   // row-group offset within panel (0 or 8)

    float Ra[16], Rb[16];
    auto loadB = [&](int p, float (&R)[16]) {
        const float* bp = w2c + (size_t)(p * 32 + rg) * DIM;
        #pragma unroll
        for (int i = 0; i < 8; ++i) R[i] = bp[(size_t)i * DIM];
        #pragma unroll
        for (int i = 0; i < 8; ++i) R[8 + i] = bp[(size_t)(16 + i) * DIM];
    };
    auto writeB = [&](int q, const float (&R)[16]) {
        bf16x8 v0, v1;
        #pragma unroll
        for (int i = 0; i < 8; ++i) { v0[i] = (short)f2bf(R[i]); v1[i] = (short)f2bf(R[8 + i]); }
        int gi0 = lane;
        int gi1 = lane + 64;
        int s0 = gi0 ^ ((gi0 >> 3) & 7);
        int s1 = gi1 ^ ((gi1 >> 3) & 7);
        *reinterpret_cast<bf16x8*>(&BsW[wv][q][s0 * 8]) = v0;
        *reinterpret_cast<bf16x8*>(&BsW[wv][q][s1 * 8]) = v1;
    };

    loadB(0, Ra);
    loadB(1, Rb);

    // stage A: thread -> (row = tid>>2, seg = tid&3 covering k 64*seg..+63)
    {
        int r = tid >> 2, seg = tid & 3;
        if (r < cnt) {
            int t = order[start + r];
            const float* xp = x + (size_t)t * DIM + seg * 64;
            #pragma unroll
            for (int g = 0; g < 8; ++g) {
                float4 a0 = *reinterpret_cast<const float4*>(xp + g * 8);
                float4 a1 = *reinterpret_cast<const float4*>(xp + g * 8 + 4);
                bf16x8 v;
                v[0] = (short)f2bf(a0.x); v[1] = (short)f2bf(a0.y);
                v[2] = (short)f2bf(a0.z); v[3] = (short)f2bf(a0.w);
                v[4] = (short)f2bf(a1.x); v[5] = (short)f2bf(a1.y);
                v[6] = (short)f2bf(a1.z); v[7] = (short)f2bf(a1.w);
                int gk = seg * 8 + g;
                int gg = r * 32 + (gk ^ (r & 7));
                *reinterpret_cast<bf16x8*>(&As[gg * 8]) = v;
            }
        }
    }
    writeB(0, Ra);
    __syncthreads();   // the ONLY barrier: A tile ready (B is wave-private)

    f32x4 acc[4][2];
    #pragma unroll
    for (int m = 0; m < 4; ++m)
        #pragma unroll
        for (int nb = 0; nb < 2; ++nb) acc[m][nb] = (f32x4){0.f, 0.f, 0.f, 0.f};

    #pragma unroll
    for (int p = 0; p < 8; ++p) {
        if (p < 6) {
            if (p & 1) loadB(p + 2, Rb); else loadB(p + 2, Ra);
        }
        bf16x8 a[4], b[2];
        #pragma unroll
        for (int nb = 0; nb < 2; ++nb) {
            int gi = kg * 32 + nb * 16 + l15;
            int si = gi ^ ((gi >> 3) & 7);
            b[nb] = *reinterpret_cast<bf16x8*>(&BsW[wv][p & 1][si * 8]);
        }
        #pragma unroll
        for (int m = 0; m < 4; ++m) if (m * 16 < cnt) {
            int row = m * 16 + l15;
            int g = row * 32 + ((p * 4 + kg) ^ (row & 7));
            a[m] = *reinterpret_cast<bf16x8*>(&As[g * 8]);
        }
        #pragma unroll
        for (int m = 0; m < 4; ++m) if (m * 16 < cnt)
            #pragma unroll
            for (int nb = 0; nb < 2; ++nb)
                acc[m][nb] = __builtin_amdgcn_mfma_f32_16x16x32_bf16(a[m], b[nb], acc[m][nb], 0, 0, 0);
        if (p < 7) {
            if (p & 1) writeB((p + 1) & 1, Ra); else writeB((p + 1) & 1, Rb);
        }
    }

    // epilogue: lvlbuf[lvl][tok][col] = pw[tok][lvl] * (acc + bias)  (plain store)
    float bias[2];
    #pragma unroll
    for (int nb = 0; nb < 2; ++nb)
        bias[nb] = b2s[((size_t)node << 8) + ch * 128 + wv * 32 + nb * 16 + l15];

    float* dst = lvlbuf + ((size_t)lvl << 19);   // 2048*256 = 1<<19 per level

    #pragma unroll
    for (int m = 0; m < 4; ++m) if (m * 16 < cnt) {
        #pragma unroll
        for (int j = 0; j < 4; ++j) {
            int r = m * 16 + kg * 4 + j;
            if (r < cnt) {
                int t = order[start + r];
                float w = pw[(size_t)t * NLEV + lvl];
                #pragma unroll
                for (int nb = 0; nb < 2; ++nb) {
                    float val = w * (acc[m][nb][j] + bias[nb]);
                    dst[(size_t)t * DIM + ch * 128 + wv * 32 + nb * 16 + l15] = val;
                }
            }
        }
    }
}

// ---------------- Kernel 4: reduce 8 level-buffers -> out ----------------
__global__ __launch_bounds__(256) void reduce_kernel(
    const float* __restrict__ lvlbuf, float* __restrict__ out)
{
    int idx = blockIdx.x * 256 + threadIdx.x;          // float4 index, < 131072
    const float4* lb = reinterpret_cast<const float4*>(lvlbuf);
    float4 s = lb[idx];
    #pragma unroll
    for (int l = 1; l < NLEV; ++l) {
        float4 v = lb[(size_t)l * 131072 + idx];
        s.x += v.x; s.y += v.y; s.z += v.z; s.w += v.w;
    }
    reinterpret_cast<float4*>(out)[idx] = s;
}

extern "C" void kernel_launch(void* const* d_in, const int* in_sizes, int n_in,
                              void* d_out, int out_size, void* d_ws, size_t ws_size,
                              hipStream_t stream) {
    const float* x   = (const float*)d_in[0];
    const float* w1s = (const float*)d_in[1];
    const float* b1s = (const float*)d_in[2];
    const float* w2s = (const float*)d_in[3];
    const float* b2s = (const float*)d_in[4];
    float* out = (float*)d_out;

    float* pw       = (float*)d_ws;                    // 2048*8 f32   (64 KB)
    int* pc         = (int*)(pw + T_TOKENS * NLEV);    // 2048
    int* order      = pc + T_TOKENS;                   // 2048
    unsigned* units = (unsigned*)(order + T_TOKENS);   // 512
    int* ucount     = (int*)(units + 512);             // 1
    float* lvlbuf   = (float*)((char*)d_ws + (1 << 20));  // 8 * 2048 * 256 f32 = 16 MB

    route_kernel<<<T_TOKENS / 4, 256, 0, stream>>>(x, w1s, b1s, pw, pc);
    sort_kernel<<<1, 256, 0, stream>>>(pc, order, units, ucount);
    out_kernel<<<1024, 256, 0, stream>>>(x, w2s, b2s, pw, order, units, ucount, lvlbuf);
    reduce_kernel<<<512, 256, 0, stream>>>(lvlbuf, out);
}